// Round 1
// baseline (830.455 us; speedup 1.0000x reference)
//
#include <hip/hip_runtime.h>

typedef __attribute__((ext_vector_type(8))) short bhalf8;
typedef __attribute__((ext_vector_type(4))) float floatx4;
typedef __attribute__((ext_vector_type(2))) float floatx2;
typedef __attribute__((ext_vector_type(4))) unsigned int uintx4;

#define MFMA16(a, b, c) __builtin_amdgcn_mfma_f32_16x16x32_bf16((a), (b), (c), 0, 0, 0)

__device__ __forceinline__ unsigned short f2bf(float f) {
  unsigned u = __builtin_bit_cast(unsigned, f);
  u += 0x7fffu + ((u >> 16) & 1u);
  return (unsigned short)(u >> 16);
}
__device__ __forceinline__ float bf2f(unsigned short h) {
  unsigned u = ((unsigned)h) << 16;
  return __builtin_bit_cast(float, u);
}

// ---------------- pack f32 -> bf16 (elementwise, 8/thread) ----------------
__global__ __launch_bounds__(256) void k_pack(const float* __restrict__ in,
                                              unsigned short* __restrict__ out, int n8) {
  int idx = blockIdx.x * blockDim.x + threadIdx.x;
  if (idx >= n8) return;
  const float* p = in + (size_t)idx * 8;
  floatx4 a = *(const floatx4*)p;
  floatx4 b = *(const floatx4*)(p + 4);
  bhalf8 r;
  r[0] = (short)f2bf(a[0]); r[1] = (short)f2bf(a[1]);
  r[2] = (short)f2bf(a[2]); r[3] = (short)f2bf(a[3]);
  r[4] = (short)f2bf(b[0]); r[5] = (short)f2bf(b[1]);
  r[6] = (short)f2bf(b[2]); r[7] = (short)f2bf(b[3]);
  *(bhalf8*)(out + (size_t)idx * 8) = r;
}

// ---------------- pack complex weight [O][I][2] f32 -> W' [2O][2I] bf16 ----
// W'[2o][2i]=wr  W'[2o][2i+1]=-wi  W'[2o+1][2i]=wi  W'[2o+1][2i+1]=wr
__global__ __launch_bounds__(256) void k_pack_w(const float* __restrict__ w,
                                                unsigned short* __restrict__ wp,
                                                int O, int I) {
  int idx = blockIdx.x * blockDim.x + threadIdx.x;
  int nI4 = I >> 2;
  if (idx >= O * nI4) return;
  int o = idx / nI4;
  int i4 = (idx - o * nI4) * 4;
  const float* src = w + ((size_t)o * I + i4) * 2;  // 4 complex = 8 floats
  floatx4 a = *(const floatx4*)src;
  floatx4 b = *(const floatx4*)(src + 4);
  bhalf8 r0, r1;
  r0[0] = (short)f2bf(a[0]); r0[1] = (short)f2bf(-a[1]);
  r0[2] = (short)f2bf(a[2]); r0[3] = (short)f2bf(-a[3]);
  r0[4] = (short)f2bf(b[0]); r0[5] = (short)f2bf(-b[1]);
  r0[6] = (short)f2bf(b[2]); r0[7] = (short)f2bf(-b[3]);
  r1[0] = (short)f2bf(a[1]); r1[1] = (short)f2bf(a[0]);
  r1[2] = (short)f2bf(a[3]); r1[3] = (short)f2bf(a[2]);
  r1[4] = (short)f2bf(b[1]); r1[5] = (short)f2bf(b[0]);
  r1[6] = (short)f2bf(b[3]); r1[7] = (short)f2bf(b[2]);
  size_t I2 = (size_t)I * 2;
  *(bhalf8*)(wp + (size_t)(2 * o) * I2 + 2 * i4) = r0;
  *(bhalf8*)(wp + (size_t)(2 * o + 1) * I2 + 2 * i4) = r1;
}

// ---------------- GEMM: C[M][N] = A[M][K] @ B[N][K]^T + bias[N], bf16 out --
// 128x128 tile, BK=32, 4 waves (2x2), acc 4x4 frags of 16x16x32.
#define GLDK 40
__global__ __launch_bounds__(256) void k_gemm(const unsigned short* __restrict__ A,
                                              const unsigned short* __restrict__ B,
                                              const float* __restrict__ bias,
                                              unsigned short* __restrict__ C,
                                              int M, int N, int K) {
  __shared__ unsigned short As[128][GLDK];
  __shared__ unsigned short Bs[128][GLDK];
  const int t = threadIdx.x;
  const int lane = t & 63, wave = t >> 6;
  const int wr = wave >> 1, wc = wave & 1;
  const int bn = blockIdx.x, bm = blockIdx.y;
  const int l15 = lane & 15, l4 = lane >> 4;

  floatx4 acc[4][4];
#pragma unroll
  for (int i = 0; i < 4; i++)
#pragma unroll
    for (int j = 0; j < 4; j++) acc[i][j] = (floatx4)0.f;

  for (int k0 = 0; k0 < K; k0 += 32) {
    bhalf8 va[2], vb[2];
#pragma unroll
    for (int s = 0; s < 2; s++) {
      int c = t + s * 256;
      int row = c >> 2, col = (c & 3) * 8;
      va[s] = *(const bhalf8*)(A + (size_t)(bm * 128 + row) * K + k0 + col);
      vb[s] = *(const bhalf8*)(B + (size_t)(bn * 128 + row) * K + k0 + col);
    }
    __syncthreads();
#pragma unroll
    for (int s = 0; s < 2; s++) {
      int c = t + s * 256;
      int row = c >> 2, col = (c & 3) * 8;
      *(bhalf8*)&As[row][col] = va[s];
      *(bhalf8*)&Bs[row][col] = vb[s];
    }
    __syncthreads();
    bhalf8 af[4], bf[4];
#pragma unroll
    for (int i = 0; i < 4; i++) {
      af[i] = *(const bhalf8*)&As[wr * 64 + i * 16 + l15][l4 * 8];
      bf[i] = *(const bhalf8*)&Bs[wc * 64 + i * 16 + l15][l4 * 8];
    }
#pragma unroll
    for (int i = 0; i < 4; i++)
#pragma unroll
      for (int j = 0; j < 4; j++) acc[i][j] = MFMA16(af[i], bf[j], acc[i][j]);
  }

  const int r0 = bm * 128 + wr * 64 + l4 * 4;
  const int c0 = bn * 128 + wc * 64 + l15;
#pragma unroll
  for (int i = 0; i < 4; i++) {
#pragma unroll
    for (int j = 0; j < 4; j++) {
      int col = c0 + j * 16;
      float bv = bias[col];
#pragma unroll
      for (int r = 0; r < 4; r++) {
        int row = r0 + i * 16 + r;
        C[(size_t)row * N + col] = f2bf(acc[i][j][r] + bv);
      }
    }
  }
}

// ---------------- complex flash attention -----------------------------------
// grid: 1024 blocks = b(8) * h(16) * qtile(8 of 64 rows); 4 waves x 16 q-rows.
__global__ __launch_bounds__(256) void k_attn(const unsigned short* __restrict__ Q,
                                              const unsigned short* __restrict__ Kg,
                                              const unsigned short* __restrict__ V,
                                              unsigned short* __restrict__ O) {
  __shared__ unsigned short Ks[32][136];
  __shared__ unsigned short Vt[128][40];
  __shared__ unsigned short Ps[4][2][16][40];  // [wave][r/i][q][key]

  const int t = threadIdx.x, lane = t & 63, wave = t >> 6;
  const int l15 = lane & 15, l4 = lane >> 4;
  const int bid = blockIdx.x;
  const int qt = bid & 7, h = (bid >> 3) & 15, b = bid >> 7;
  const int colbase = h * 128;
  const int qrow0 = b * 512 + qt * 64 + wave * 16;

  // Q fragments (A-operand: row = lane&15, 8 contiguous interleaved features)
  bhalf8 qf[4];
  {
    const unsigned short* qp = Q + (size_t)(qrow0 + l15) * 2048 + colbase + l4 * 8;
#pragma unroll
    for (int ks = 0; ks < 4; ks++) qf[ks] = *(const bhalf8*)(qp + ks * 32);
  }

  float m_s[2][4], l_s[2][4];
#pragma unroll
  for (int c = 0; c < 2; c++)
#pragma unroll
    for (int r = 0; r < 4; r++) { m_s[c][r] = -1e30f; l_s[c][r] = 0.f; }
  floatx4 oacc[2][8];
#pragma unroll
  for (int c = 0; c < 2; c++)
#pragma unroll
    for (int n = 0; n < 8; n++) oacc[c][n] = (floatx4)0.f;

  for (int kb = 0; kb < 16; kb++) {
    __syncthreads();  // protect K/Vt reuse across iterations
    // stage K tile [32 keys][128 feat]
#pragma unroll
    for (int s = 0; s < 2; s++) {
      int c = t + s * 256;
      int kr = c >> 4, jc = (c & 15) * 8;
      *(bhalf8*)&Ks[kr][jc] =
          *(const bhalf8*)(Kg + (size_t)(b * 512 + kb * 32 + kr) * 2048 + colbase + jc);
    }
    // stage transposed V tile: Vt[j][k] = V[k][j]
#pragma unroll
    for (int s = 0; s < 2; s++) {
      int c = t + s * 256;
      int kr = c & 31, j0 = (c >> 5) * 8;
      bhalf8 vv = *(const bhalf8*)(V + (size_t)(b * 512 + kb * 32 + kr) * 2048 + colbase + j0);
#pragma unroll
      for (int i2 = 0; i2 < 8; i2++) Vt[j0 + i2][kr] = (unsigned short)vv[i2];
    }
    __syncthreads();

    // QK^T: Sr uses sign-flipped-odd K, Si uses pair-swapped K
    floatx4 sacc[2][2];
#pragma unroll
    for (int c = 0; c < 2; c++) { sacc[c][0] = (floatx4)0.f; sacc[c][1] = (floatx4)0.f; }
#pragma unroll
    for (int ks = 0; ks < 4; ks++) {
#pragma unroll
      for (int n = 0; n < 2; n++) {
        bhalf8 kf = *(const bhalf8*)&Ks[n * 16 + l15][ks * 32 + l4 * 8];
        uintx4 ku = __builtin_bit_cast(uintx4, kf);
        uintx4 kneg = ku ^ 0x80000000u;             // negate odd-j (imag) slots
        uintx4 kswp = (ku >> 16) | (ku << 16);      // swap (r,i) pairs
        sacc[0][n] = MFMA16(qf[ks], __builtin_bit_cast(bhalf8, kneg), sacc[0][n]);
        sacc[1][n] = MFMA16(qf[ks], __builtin_bit_cast(bhalf8, kswp), sacc[1][n]);
      }
    }

    // online softmax for both components
    const float scale = 0.125f;
#pragma unroll
    for (int comp = 0; comp < 2; comp++) {
#pragma unroll
      for (int r = 0; r < 4; r++) {
        float v0 = sacc[comp][0][r] * scale;
        float v1 = sacc[comp][1][r] * scale;
        float vmax = fmaxf(v0, v1);
#pragma unroll
        for (int off = 1; off < 16; off <<= 1) vmax = fmaxf(vmax, __shfl_xor(vmax, off, 64));
        float mnew = fmaxf(m_s[comp][r], vmax);
        float cr = __expf(m_s[comp][r] - mnew);
        float p0 = __expf(v0 - mnew), p1 = __expf(v1 - mnew);
        float ps = p0 + p1;
#pragma unroll
        for (int off = 1; off < 16; off <<= 1) ps += __shfl_xor(ps, off, 64);
        l_s[comp][r] = l_s[comp][r] * cr + ps;
        m_s[comp][r] = mnew;
#pragma unroll
        for (int nn = 0; nn < 8; nn++) oacc[comp][nn][r] *= cr;
        int qr = l4 * 4 + r;
        Ps[wave][comp][qr][l15] = f2bf(p0);
        Ps[wave][comp][qr][16 + l15] = f2bf(p1);
      }
    }
    __syncthreads();

    // PV: O += Pr @ Vt  +  Pi @ VtB (VtB = swapped-neighbor, sign per parity)
    bhalf8 par = *(const bhalf8*)&Ps[wave][0][l15][l4 * 8];
    bhalf8 pai = *(const bhalf8*)&Ps[wave][1][l15][l4 * 8];
#pragma unroll
    for (int nn = 0; nn < 8; nn++) {
      bhalf8 vf = *(const bhalf8*)&Vt[nn * 16 + l15][l4 * 8];
      uintx4 vu = __builtin_bit_cast(uintx4, vf);
      uintx4 vp;
#pragma unroll
      for (int i2 = 0; i2 < 4; i2++) vp[i2] = (unsigned)__shfl_xor((int)vu[i2], 1, 64);
      if (!(lane & 1)) vp ^= 0x80008000u;  // even j: -V[k][j+1]
      oacc[0][nn] = MFMA16(par, vf, oacc[0][nn]);
      oacc[1][nn] = MFMA16(pai, __builtin_bit_cast(bhalf8, vp), oacc[1][nn]);
    }
  }

  // combine: O = Or_part/l_r + Oi_part/l_i
#pragma unroll
  for (int nn = 0; nn < 8; nn++) {
#pragma unroll
    for (int r = 0; r < 4; r++) {
      float o = oacc[0][nn][r] / l_s[0][r] + oacc[1][nn][r] / l_s[1][r];
      int row = qrow0 + l4 * 4 + r;
      int col = colbase + nn * 16 + l15;
      O[(size_t)row * 2048 + col] = f2bf(o);
    }
  }
}

// ---------------- block reduction of 4 values across 256 threads ------------
__device__ __forceinline__ void block_reduce_4(float* v, float* sbuf, int t) {
  int lane = t & 63, wave = t >> 6;
#pragma unroll
  for (int i = 0; i < 4; i++) {
    float x = v[i];
#pragma unroll
    for (int off = 32; off > 0; off >>= 1) x += __shfl_xor(x, off, 64);
    if (lane == 0) sbuf[wave * 4 + i] = x;
  }
  __syncthreads();
#pragma unroll
  for (int i = 0; i < 4; i++) v[i] = sbuf[i] + sbuf[4 + i] + sbuf[8 + i] + sbuf[12 + i];
  __syncthreads();
}

// ---------------- post-attention: (O+q) -> LN0 -> (+x) -> LN1 ---------------
__global__ __launch_bounds__(256) void k_ln_attn(const unsigned short* __restrict__ O,
                                                 const float* __restrict__ qin,
                                                 const float* __restrict__ xin,
                                                 const float* __restrict__ g,
                                                 const float* __restrict__ bb,
                                                 float* __restrict__ xr2,
                                                 unsigned short* __restrict__ xr2b) {
  __shared__ float sbuf[16];
  const int row = blockIdx.x, t = threadIdx.x;
  const size_t base = (size_t)row * 2048;
  float tr[4], ti[4], acc[4] = {0.f, 0.f, 0.f, 0.f};
#pragma unroll
  for (int k = 0; k < 4; k++) {
    int d = k * 256 + t;
    unsigned op = *(const unsigned*)(O + base + 2 * d);
    floatx2 qp = *(const floatx2*)(qin + base + 2 * d);
    float a = bf2f((unsigned short)(op & 0xffffu)) + qp[0];
    float c = bf2f((unsigned short)(op >> 16)) + qp[1];
    tr[k] = a; ti[k] = c;
    acc[0] += a; acc[1] += a * a; acc[2] += c; acc[3] += c * c;
  }
  block_reduce_4(acc, sbuf, t);
  float mr = acc[0] * (1.f / 1024.f), vr = acc[1] * (1.f / 1024.f) - mr * mr;
  float mi = acc[2] * (1.f / 1024.f), vi = acc[3] * (1.f / 1024.f) - mi * mi;
  float ir = rsqrtf(vr + 1e-5f), ii = rsqrtf(vi + 1e-5f);
  float ur[4], ui[4], a2[4] = {0.f, 0.f, 0.f, 0.f};
#pragma unroll
  for (int k = 0; k < 4; k++) {
    int d = k * 256 + t;
    float u_r = (tr[k] - mr) * ir * g[d] + bb[d];
    float u_i = (ti[k] - mi) * ii * g[1024 + d] + bb[1024 + d];
    floatx2 xp = *(const floatx2*)(xin + base + 2 * d);
    float v_r = xp[0] + u_r, v_i = xp[1] + u_i;
    ur[k] = v_r; ui[k] = v_i;
    a2[0] += v_r; a2[1] += v_r * v_r; a2[2] += v_i; a2[3] += v_i * v_i;
  }
  block_reduce_4(a2, sbuf, t);
  float mr2 = a2[0] * (1.f / 1024.f), vr2 = a2[1] * (1.f / 1024.f) - mr2 * mr2;
  float mi2 = a2[2] * (1.f / 1024.f), vi2 = a2[3] * (1.f / 1024.f) - mi2 * mi2;
  float ir2 = rsqrtf(vr2 + 1e-5f), ii2 = rsqrtf(vi2 + 1e-5f);
#pragma unroll
  for (int k = 0; k < 4; k++) {
    int d = k * 256 + t;
    float w_r = (ur[k] - mr2) * ir2 * g[2048 + d] + bb[2048 + d];
    float w_i = (ui[k] - mi2) * ii2 * g[3072 + d] + bb[3072 + d];
    floatx2 o; o[0] = w_r; o[1] = w_i;
    *(floatx2*)(xr2 + base + 2 * d) = o;
    unsigned pk = ((unsigned)f2bf(w_i) << 16) | (unsigned)f2bf(w_r);
    *(unsigned*)(xr2b + base + 2 * d) = pk;
  }
}

// ---------------- modReLU-style activation, in place on bf16 pairs ----------
__global__ __launch_bounds__(256) void k_act(unsigned int* __restrict__ h) {
  size_t idx = (size_t)blockIdx.x * blockDim.x + threadIdx.x;  // 4 pairs each
  uintx4 v = *(uintx4*)(h + idx * 4);
#pragma unroll
  for (int i = 0; i < 4; i++) {
    float hr = bf2f((unsigned short)(v[i] & 0xffffu));
    float hi = bf2f((unsigned short)(v[i] >> 16));
    float mag = sqrtf(hr * hr + hi * hi);
    float nr = 0.5f * (hr + mag), ni = 0.5f * hi;
    v[i] = ((unsigned)f2bf(ni) << 16) | (unsigned)f2bf(nr);
  }
  *(uintx4*)(h + idx * 4) = v;
}

// ---------------- final: (xr2 + m) -> LN2 -> out ----------------------------
__global__ __launch_bounds__(256) void k_ln_final(const unsigned short* __restrict__ Mh,
                                                  const float* __restrict__ xr2,
                                                  const float* __restrict__ g,
                                                  const float* __restrict__ bb,
                                                  float* __restrict__ out) {
  __shared__ float sbuf[16];
  const int row = blockIdx.x, t = threadIdx.x;
  const size_t base = (size_t)row * 2048;
  float tr[4], ti[4], acc[4] = {0.f, 0.f, 0.f, 0.f};
#pragma unroll
  for (int k = 0; k < 4; k++) {
    int d = k * 256 + t;
    unsigned mp = *(const unsigned*)(Mh + base + 2 * d);
    floatx2 xp = *(const floatx2*)(xr2 + base + 2 * d);
    float a = xp[0] + bf2f((unsigned short)(mp & 0xffffu));
    float c = xp[1] + bf2f((unsigned short)(mp >> 16));
    tr[k] = a; ti[k] = c;
    acc[0] += a; acc[1] += a * a; acc[2] += c; acc[3] += c * c;
  }
  block_reduce_4(acc, sbuf, t);
  float mr = acc[0] * (1.f / 1024.f), vr = acc[1] * (1.f / 1024.f) - mr * mr;
  float mi = acc[2] * (1.f / 1024.f), vi = acc[3] * (1.f / 1024.f) - mi * mi;
  float ir = rsqrtf(vr + 1e-5f), ii = rsqrtf(vi + 1e-5f);
#pragma unroll
  for (int k = 0; k < 4; k++) {
    int d = k * 256 + t;
    float w_r = (tr[k] - mr) * ir * g[4096 + d] + bb[4096 + d];
    float w_i = (ti[k] - mi) * ii * g[5120 + d] + bb[5120 + d];
    floatx2 o; o[0] = w_r; o[1] = w_i;
    *(floatx2*)(out + base + 2 * d) = o;
  }
}

extern "C" void kernel_launch(void* const* d_in, const int* in_sizes, int n_in,
                              void* d_out, int out_size, void* d_ws, size_t ws_size,
                              hipStream_t stream) {
  const float* x   = (const float*)d_in[0];
  const float* qy  = (const float*)d_in[1];
  const float* wq  = (const float*)d_in[2];
  const float* bq  = (const float*)d_in[3];
  const float* wk  = (const float*)d_in[4];
  const float* bk  = (const float*)d_in[5];
  const float* wv  = (const float*)d_in[6];
  const float* bv  = (const float*)d_in[7];
  const float* wfc = (const float*)d_in[8];
  const float* bfc = (const float*)d_in[9];
  const float* wpj = (const float*)d_in[10];
  const float* bpj = (const float*)d_in[11];
  const float* lng = (const float*)d_in[12];
  const float* lnb = (const float*)d_in[13];

  const size_t SZ_TOK = (size_t)4096 * 2048;  // 8.39M elems
  unsigned short* ws0 = (unsigned short*)d_ws;
  unsigned short* xqb = ws0;                       // packed query (later: O)
  unsigned short* xb  = xqb + SZ_TOK;              // packed x     (later: m)
  unsigned short* wp  = xb + SZ_TOK;               // packed weight slot (16.8M elems)
  unsigned short* Qb  = wp + (size_t)8192 * 2048;
  unsigned short* Kb  = Qb + SZ_TOK;
  unsigned short* Vb  = Kb + SZ_TOK;
  unsigned short* hb  = Vb + SZ_TOK;               // fc out, 4096x8192
  unsigned short* Ob  = xqb;                       // alias after Q GEMM
  float*          xr2 = (float*)Qb;                // alias after attention (spans Q+K)
  unsigned short* x2b = Vb;                        // alias after attention
  unsigned short* mb  = xb;                        // alias after V GEMM

  const int n8 = (int)(SZ_TOK / 8);
  k_pack<<<n8 / 256, 256, 0, stream>>>(qy, xqb, n8);
  k_pack<<<n8 / 256, 256, 0, stream>>>(x, xb, n8);

  dim3 gQ(16, 32);  // N=2048, M=4096
  k_pack_w<<<1024, 256, 0, stream>>>(wq, wp, 1024, 1024);
  k_gemm<<<gQ, 256, 0, stream>>>(xqb, wp, bq, Qb, 4096, 2048, 2048);
  k_pack_w<<<1024, 256, 0, stream>>>(wk, wp, 1024, 1024);
  k_gemm<<<gQ, 256, 0, stream>>>(xb, wp, bk, Kb, 4096, 2048, 2048);
  k_pack_w<<<1024, 256, 0, stream>>>(wv, wp, 1024, 1024);
  k_gemm<<<gQ, 256, 0, stream>>>(xb, wp, bv, Vb, 4096, 2048, 2048);

  k_attn<<<1024, 256, 0, stream>>>(Qb, Kb, Vb, Ob);
  k_ln_attn<<<4096, 256, 0, stream>>>(Ob, qy, x, lng, lnb, xr2, x2b);

  k_pack_w<<<4096, 256, 0, stream>>>(wfc, wp, 4096, 1024);
  dim3 gF(64, 32);  // N=8192, M=4096
  k_gemm<<<gF, 256, 0, stream>>>(x2b, wp, bfc, hb, 4096, 8192, 2048);
  k_act<<<16384, 256, 0, stream>>>((unsigned int*)hb);

  k_pack_w<<<4096, 256, 0, stream>>>(wpj, wp, 1024, 4096);
  dim3 gP(16, 32);  // N=2048, M=4096, K=8192
  k_gemm<<<gP, 256, 0, stream>>>(hb, wp, bpj, mb, 4096, 2048, 8192);

  k_ln_final<<<4096, 256, 0, stream>>>(mb, xr2, lng, lnb, (float*)d_out);
}

// Round 2
// 805.723 us; speedup vs baseline: 1.0307x; 1.0307x over previous
//
#include <hip/hip_runtime.h>

typedef __attribute__((ext_vector_type(8))) short bhalf8;
typedef __attribute__((ext_vector_type(4))) float floatx4;
typedef __attribute__((ext_vector_type(2))) float floatx2;
typedef __attribute__((ext_vector_type(4))) unsigned int uintx4;

#define MFMA16(a, b, c) __builtin_amdgcn_mfma_f32_16x16x32_bf16((a), (b), (c), 0, 0, 0)

__device__ __forceinline__ unsigned short f2bf(float f) {
  unsigned u = __builtin_bit_cast(unsigned, f);
  u += 0x7fffu + ((u >> 16) & 1u);
  return (unsigned short)(u >> 16);
}
__device__ __forceinline__ float bf2f(unsigned short h) {
  unsigned u = ((unsigned)h) << 16;
  return __builtin_bit_cast(float, u);
}

// async global->LDS, 16B per lane; LDS dest is wave-uniform base + lane*16
__device__ __forceinline__ void gload_lds16(const unsigned short* g, unsigned short* l) {
  __builtin_amdgcn_global_load_lds((__attribute__((address_space(1))) void*)(g),
                                   (__attribute__((address_space(3))) void*)(l), 16, 0, 0);
}

// ---------------- pack f32 -> bf16 (elementwise, 8/thread) ----------------
__global__ __launch_bounds__(256) void k_pack(const float* __restrict__ in,
                                              unsigned short* __restrict__ out, int n8) {
  int idx = blockIdx.x * blockDim.x + threadIdx.x;
  if (idx >= n8) return;
  const float* p = in + (size_t)idx * 8;
  floatx4 a = *(const floatx4*)p;
  floatx4 b = *(const floatx4*)(p + 4);
  bhalf8 r;
  r[0] = (short)f2bf(a[0]); r[1] = (short)f2bf(a[1]);
  r[2] = (short)f2bf(a[2]); r[3] = (short)f2bf(a[3]);
  r[4] = (short)f2bf(b[0]); r[5] = (short)f2bf(b[1]);
  r[6] = (short)f2bf(b[2]); r[7] = (short)f2bf(b[3]);
  *(bhalf8*)(out + (size_t)idx * 8) = r;
}

// ---------------- pack complex weight [O][I][2] f32 -> W' [2O][2I] bf16 ----
// W'[2o][2i]=wr  W'[2o][2i+1]=-wi  W'[2o+1][2i]=wi  W'[2o+1][2i+1]=wr
__global__ __launch_bounds__(256) void k_pack_w(const float* __restrict__ w,
                                                unsigned short* __restrict__ wp,
                                                int O, int I) {
  int idx = blockIdx.x * blockDim.x + threadIdx.x;
  int nI4 = I >> 2;
  if (idx >= O * nI4) return;
  int o = idx / nI4;
  int i4 = (idx - o * nI4) * 4;
  const float* src = w + ((size_t)o * I + i4) * 2;  // 4 complex = 8 floats
  floatx4 a = *(const floatx4*)src;
  floatx4 b = *(const floatx4*)(src + 4);
  bhalf8 r0, r1;
  r0[0] = (short)f2bf(a[0]); r0[1] = (short)f2bf(-a[1]);
  r0[2] = (short)f2bf(a[2]); r0[3] = (short)f2bf(-a[3]);
  r0[4] = (short)f2bf(b[0]); r0[5] = (short)f2bf(-b[1]);
  r0[6] = (short)f2bf(b[2]); r0[7] = (short)f2bf(-b[3]);
  r1[0] = (short)f2bf(a[1]); r1[1] = (short)f2bf(a[0]);
  r1[2] = (short)f2bf(a[3]); r1[3] = (short)f2bf(a[2]);
  r1[4] = (short)f2bf(b[1]); r1[5] = (short)f2bf(b[0]);
  r1[6] = (short)f2bf(b[3]); r1[7] = (short)f2bf(b[2]);
  size_t I2 = (size_t)I * 2;
  *(bhalf8*)(wp + (size_t)(2 * o) * I2 + 2 * i4) = r0;
  *(bhalf8*)(wp + (size_t)(2 * o + 1) * I2 + 2 * i4) = r1;
}

// ---------------- GEMM: C[M][N] = A[M][K] @ B[N][K]^T + bias[N], bf16 out --
// m97 structure: 128x128 tile, BK=32, 4 waves (2x2), linear LDS [128][32],
// global_load_lds width=16 staging, 2 barriers per K-step, 16 MFMA/K-step.
__global__ __launch_bounds__(256) void k_gemm(const unsigned short* __restrict__ A,
                                              const unsigned short* __restrict__ B,
                                              const float* __restrict__ bias,
                                              unsigned short* __restrict__ C,
                                              int M, int N, int K) {
  __shared__ unsigned short As[128 * 32];
  __shared__ unsigned short Bs[128 * 32];
  const int t = threadIdx.x;
  const int lane = t & 63, wave = t >> 6;
  const int wr = wave >> 1, wc = wave & 1;
  const int bn = blockIdx.x, bm = blockIdx.y;
  const int l15 = lane & 15, l4 = lane >> 4;

  floatx4 acc[4][4];
#pragma unroll
  for (int i = 0; i < 4; i++)
#pragma unroll
    for (int j = 0; j < 4; j++) acc[i][j] = (floatx4)0.f;

  // staging geometry: chunk c = r*256 + t covers LDS shorts [c*8, c*8+8)
  // = row c>>2, col (c&3)*8 of the row-major [128][32] tile.
  const int srow = t >> 2, scol = (t & 3) << 3;
  const unsigned short* ga = A + (size_t)(bm * 128 + srow) * K + scol;
  const unsigned short* gb = B + (size_t)(bn * 128 + srow) * K + scol;
  const size_t rstep = (size_t)64 * K;  // +64 rows for round 1
  unsigned short* lA0 = As + (size_t)(wave * 64) * 8;
  unsigned short* lB0 = Bs + (size_t)(wave * 64) * 8;

  for (int k0 = 0; k0 < K; k0 += 32) {
    __syncthreads();  // all waves done reading LDS from previous step
    gload_lds16(ga + k0, lA0);
    gload_lds16(ga + k0 + rstep, lA0 + 256 * 8);
    gload_lds16(gb + k0, lB0);
    gload_lds16(gb + k0 + rstep, lB0 + 256 * 8);
    __syncthreads();  // vmcnt(0) drained before barrier -> tile resident
    bhalf8 af[4], bfr[4];
#pragma unroll
    for (int i = 0; i < 4; i++) {
      af[i] = *(const bhalf8*)&As[(wr * 64 + i * 16 + l15) * 32 + l4 * 8];
      bfr[i] = *(const bhalf8*)&Bs[(wc * 64 + i * 16 + l15) * 32 + l4 * 8];
    }
#pragma unroll
    for (int i = 0; i < 4; i++)
#pragma unroll
      for (int j = 0; j < 4; j++) acc[i][j] = MFMA16(af[i], bfr[j], acc[i][j]);
  }

  const int r0 = bm * 128 + wr * 64 + l4 * 4;
  const int c0 = bn * 128 + wc * 64 + l15;
#pragma unroll
  for (int i = 0; i < 4; i++) {
#pragma unroll
    for (int j = 0; j < 4; j++) {
      int col = c0 + j * 16;
      float bv = bias[col];
#pragma unroll
      for (int r = 0; r < 4; r++) {
        int row = r0 + i * 16 + r;
        C[(size_t)row * N + col] = f2bf(acc[i][j][r] + bv);
      }
    }
  }
}

// ---------------- complex flash attention -----------------------------------
// grid: 1024 blocks = b(8) * h(16) * qtile(8 of 64 rows); 4 waves x 16 q-rows.
__global__ __launch_bounds__(256) void k_attn(const unsigned short* __restrict__ Q,
                                              const unsigned short* __restrict__ Kg,
                                              const unsigned short* __restrict__ V,
                                              unsigned short* __restrict__ O) {
  __shared__ unsigned short Ks[32][136];
  __shared__ unsigned short Vt[128][40];
  __shared__ unsigned short Ps[4][2][16][40];  // [wave][r/i][q][key]

  const int t = threadIdx.x, lane = t & 63, wave = t >> 6;
  const int l15 = lane & 15, l4 = lane >> 4;
  const int bid = blockIdx.x;
  const int qt = bid & 7, h = (bid >> 3) & 15, b = bid >> 7;
  const int colbase = h * 128;
  const int qrow0 = b * 512 + qt * 64 + wave * 16;

  // Q fragments (A-operand: row = lane&15, 8 contiguous interleaved features)
  bhalf8 qf[4];
  {
    const unsigned short* qp = Q + (size_t)(qrow0 + l15) * 2048 + colbase + l4 * 8;
#pragma unroll
    for (int ks = 0; ks < 4; ks++) qf[ks] = *(const bhalf8*)(qp + ks * 32);
  }

  float m_s[2][4], l_s[2][4];
#pragma unroll
  for (int c = 0; c < 2; c++)
#pragma unroll
    for (int r = 0; r < 4; r++) { m_s[c][r] = -1e30f; l_s[c][r] = 0.f; }
  floatx4 oacc[2][8];
#pragma unroll
  for (int c = 0; c < 2; c++)
#pragma unroll
    for (int n = 0; n < 8; n++) oacc[c][n] = (floatx4)0.f;

  for (int kb = 0; kb < 16; kb++) {
    __syncthreads();  // protect K/Vt reuse across iterations
    // stage K tile [32 keys][128 feat]
#pragma unroll
    for (int s = 0; s < 2; s++) {
      int c = t + s * 256;
      int kr = c >> 4, jc = (c & 15) * 8;
      *(bhalf8*)&Ks[kr][jc] =
          *(const bhalf8*)(Kg + (size_t)(b * 512 + kb * 32 + kr) * 2048 + colbase + jc);
    }
    // stage transposed V tile: Vt[j][k] = V[k][j]
#pragma unroll
    for (int s = 0; s < 2; s++) {
      int c = t + s * 256;
      int kr = c & 31, j0 = (c >> 5) * 8;
      bhalf8 vv = *(const bhalf8*)(V + (size_t)(b * 512 + kb * 32 + kr) * 2048 + colbase + j0);
#pragma unroll
      for (int i2 = 0; i2 < 8; i2++) Vt[j0 + i2][kr] = (unsigned short)vv[i2];
    }
    __syncthreads();

    // QK^T: Sr uses sign-flipped-odd K, Si uses pair-swapped K
    floatx4 sacc[2][2];
#pragma unroll
    for (int c = 0; c < 2; c++) { sacc[c][0] = (floatx4)0.f; sacc[c][1] = (floatx4)0.f; }
#pragma unroll
    for (int ks = 0; ks < 4; ks++) {
#pragma unroll
      for (int n = 0; n < 2; n++) {
        bhalf8 kf = *(const bhalf8*)&Ks[n * 16 + l15][ks * 32 + l4 * 8];
        uintx4 ku = __builtin_bit_cast(uintx4, kf);
        uintx4 kneg = ku ^ 0x80000000u;             // negate odd-j (imag) slots
        uintx4 kswp = (ku >> 16) | (ku << 16);      // swap (r,i) pairs
        sacc[0][n] = MFMA16(qf[ks], __builtin_bit_cast(bhalf8, kneg), sacc[0][n]);
        sacc[1][n] = MFMA16(qf[ks], __builtin_bit_cast(bhalf8, kswp), sacc[1][n]);
      }
    }

    // online softmax for both components
    const float scale = 0.125f;
#pragma unroll
    for (int comp = 0; comp < 2; comp++) {
#pragma unroll
      for (int r = 0; r < 4; r++) {
        float v0 = sacc[comp][0][r] * scale;
        float v1 = sacc[comp][1][r] * scale;
        float vmax = fmaxf(v0, v1);
#pragma unroll
        for (int off = 1; off < 16; off <<= 1) vmax = fmaxf(vmax, __shfl_xor(vmax, off, 64));
        float mnew = fmaxf(m_s[comp][r], vmax);
        float cr = __expf(m_s[comp][r] - mnew);
        float p0 = __expf(v0 - mnew), p1 = __expf(v1 - mnew);
        float ps = p0 + p1;
#pragma unroll
        for (int off = 1; off < 16; off <<= 1) ps += __shfl_xor(ps, off, 64);
        l_s[comp][r] = l_s[comp][r] * cr + ps;
        m_s[comp][r] = mnew;
#pragma unroll
        for (int nn = 0; nn < 8; nn++) oacc[comp][nn][r] *= cr;
        int qr = l4 * 4 + r;
        Ps[wave][comp][qr][l15] = f2bf(p0);
        Ps[wave][comp][qr][16 + l15] = f2bf(p1);
      }
    }
    __syncthreads();

    // PV: O += Pr @ Vt  +  Pi @ VtB (VtB = swapped-neighbor, sign per parity)
    bhalf8 par = *(const bhalf8*)&Ps[wave][0][l15][l4 * 8];
    bhalf8 pai = *(const bhalf8*)&Ps[wave][1][l15][l4 * 8];
#pragma unroll
    for (int nn = 0; nn < 8; nn++) {
      bhalf8 vf = *(const bhalf8*)&Vt[nn * 16 + l15][l4 * 8];
      uintx4 vu = __builtin_bit_cast(uintx4, vf);
      uintx4 vp;
#pragma unroll
      for (int i2 = 0; i2 < 4; i2++) vp[i2] = (unsigned)__shfl_xor((int)vu[i2], 1, 64);
      if (!(lane & 1)) vp ^= 0x80008000u;  // even j: -V[k][j+1]
      oacc[0][nn] = MFMA16(par, vf, oacc[0][nn]);
      oacc[1][nn] = MFMA16(pai, __builtin_bit_cast(bhalf8, vp), oacc[1][nn]);
    }
  }

  // combine: O = Or_part/l_r + Oi_part/l_i
#pragma unroll
  for (int nn = 0; nn < 8; nn++) {
#pragma unroll
    for (int r = 0; r < 4; r++) {
      float o = oacc[0][nn][r] / l_s[0][r] + oacc[1][nn][r] / l_s[1][r];
      int row = qrow0 + l4 * 4 + r;
      int col = colbase + nn * 16 + l15;
      O[(size_t)row * 2048 + col] = f2bf(o);
    }
  }
}

// ---------------- block reduction of 4 values across 256 threads ------------
__device__ __forceinline__ void block_reduce_4(float* v, float* sbuf, int t) {
  int lane = t & 63, wave = t >> 6;
#pragma unroll
  for (int i = 0; i < 4; i++) {
    float x = v[i];
#pragma unroll
    for (int off = 32; off > 0; off >>= 1) x += __shfl_xor(x, off, 64);
    if (lane == 0) sbuf[wave * 4 + i] = x;
  }
  __syncthreads();
#pragma unroll
  for (int i = 0; i < 4; i++) v[i] = sbuf[i] + sbuf[4 + i] + sbuf[8 + i] + sbuf[12 + i];
  __syncthreads();
}

// ---------------- post-attention: (O+q) -> LN0 -> (+x) -> LN1 ---------------
__global__ __launch_bounds__(256) void k_ln_attn(const unsigned short* __restrict__ O,
                                                 const float* __restrict__ qin,
                                                 const float* __restrict__ xin,
                                                 const float* __restrict__ g,
                                                 const float* __restrict__ bb,
                                                 float* __restrict__ xr2,
                                                 unsigned short* __restrict__ xr2b) {
  __shared__ float sbuf[16];
  const int row = blockIdx.x, t = threadIdx.x;
  const size_t base = (size_t)row * 2048;
  float tr[4], ti[4], acc[4] = {0.f, 0.f, 0.f, 0.f};
#pragma unroll
  for (int k = 0; k < 4; k++) {
    int d = k * 256 + t;
    unsigned op = *(const unsigned*)(O + base + 2 * d);
    floatx2 qp = *(const floatx2*)(qin + base + 2 * d);
    float a = bf2f((unsigned short)(op & 0xffffu)) + qp[0];
    float c = bf2f((unsigned short)(op >> 16)) + qp[1];
    tr[k] = a; ti[k] = c;
    acc[0] += a; acc[1] += a * a; acc[2] += c; acc[3] += c * c;
  }
  block_reduce_4(acc, sbuf, t);
  float mr = acc[0] * (1.f / 1024.f), vr = acc[1] * (1.f / 1024.f) - mr * mr;
  float mi = acc[2] * (1.f / 1024.f), vi = acc[3] * (1.f / 1024.f) - mi * mi;
  float ir = rsqrtf(vr + 1e-5f), ii = rsqrtf(vi + 1e-5f);
  float ur[4], ui[4], a2[4] = {0.f, 0.f, 0.f, 0.f};
#pragma unroll
  for (int k = 0; k < 4; k++) {
    int d = k * 256 + t;
    float u_r = (tr[k] - mr) * ir * g[d] + bb[d];
    float u_i = (ti[k] - mi) * ii * g[1024 + d] + bb[1024 + d];
    floatx2 xp = *(const floatx2*)(xin + base + 2 * d);
    float v_r = xp[0] + u_r, v_i = xp[1] + u_i;
    ur[k] = v_r; ui[k] = v_i;
    a2[0] += v_r; a2[1] += v_r * v_r; a2[2] += v_i; a2[3] += v_i * v_i;
  }
  block_reduce_4(a2, sbuf, t);
  float mr2 = a2[0] * (1.f / 1024.f), vr2 = a2[1] * (1.f / 1024.f) - mr2 * mr2;
  float mi2 = a2[2] * (1.f / 1024.f), vi2 = a2[3] * (1.f / 1024.f) - mi2 * mi2;
  float ir2 = rsqrtf(vr2 + 1e-5f), ii2 = rsqrtf(vi2 + 1e-5f);
#pragma unroll
  for (int k = 0; k < 4; k++) {
    int d = k * 256 + t;
    float w_r = (ur[k] - mr2) * ir2 * g[2048 + d] + bb[2048 + d];
    float w_i = (ui[k] - mi2) * ii2 * g[3072 + d] + bb[3072 + d];
    floatx2 o; o[0] = w_r; o[1] = w_i;
    *(floatx2*)(xr2 + base + 2 * d) = o;
    unsigned pk = ((unsigned)f2bf(w_i) << 16) | (unsigned)f2bf(w_r);
    *(unsigned*)(xr2b + base + 2 * d) = pk;
  }
}

// ---------------- modReLU-style activation, in place on bf16 pairs ----------
__global__ __launch_bounds__(256) void k_act(unsigned int* __restrict__ h) {
  size_t idx = (size_t)blockIdx.x * blockDim.x + threadIdx.x;  // 4 pairs each
  uintx4 v = *(uintx4*)(h + idx * 4);
#pragma unroll
  for (int i = 0; i < 4; i++) {
    float hr = bf2f((unsigned short)(v[i] & 0xffffu));
    float hi = bf2f((unsigned short)(v[i] >> 16));
    float mag = sqrtf(hr * hr + hi * hi);
    float nr = 0.5f * (hr + mag), ni = 0.5f * hi;
    v[i] = ((unsigned)f2bf(ni) << 16) | (unsigned)f2bf(nr);
  }
  *(uintx4*)(h + idx * 4) = v;
}

// ---------------- final: (xr2 + m) -> LN2 -> out ----------------------------
__global__ __launch_bounds__(256) void k_ln_final(const unsigned short* __restrict__ Mh,
                                                  const float* __restrict__ xr2,
                                                  const float* __restrict__ g,
                                                  const float* __restrict__ bb,
                                                  float* __restrict__ out) {
  __shared__ float sbuf[16];
  const int row = blockIdx.x, t = threadIdx.x;
  const size_t base = (size_t)row * 2048;
  float tr[4], ti[4], acc[4] = {0.f, 0.f, 0.f, 0.f};
#pragma unroll
  for (int k = 0; k < 4; k++) {
    int d = k * 256 + t;
    unsigned mp = *(const unsigned*)(Mh + base + 2 * d);
    floatx2 xp = *(const floatx2*)(xr2 + base + 2 * d);
    float a = xp[0] + bf2f((unsigned short)(mp & 0xffffu));
    float c = xp[1] + bf2f((unsigned short)(mp >> 16));
    tr[k] = a; ti[k] = c;
    acc[0] += a; acc[1] += a * a; acc[2] += c; acc[3] += c * c;
  }
  block_reduce_4(acc, sbuf, t);
  float mr = acc[0] * (1.f / 1024.f), vr = acc[1] * (1.f / 1024.f) - mr * mr;
  float mi = acc[2] * (1.f / 1024.f), vi = acc[3] * (1.f / 1024.f) - mi * mi;
  float ir = rsqrtf(vr + 1e-5f), ii = rsqrtf(vi + 1e-5f);
#pragma unroll
  for (int k = 0; k < 4; k++) {
    int d = k * 256 + t;
    float w_r = (tr[k] - mr) * ir * g[4096 + d] + bb[4096 + d];
    float w_i = (ti[k] - mi) * ii * g[5120 + d] + bb[5120 + d];
    floatx2 o; o[0] = w_r; o[1] = w_i;
    *(floatx2*)(out + base + 2 * d) = o;
  }
}

extern "C" void kernel_launch(void* const* d_in, const int* in_sizes, int n_in,
                              void* d_out, int out_size, void* d_ws, size_t ws_size,
                              hipStream_t stream) {
  const float* x   = (const float*)d_in[0];
  const float* qy  = (const float*)d_in[1];
  const float* wq  = (const float*)d_in[2];
  const float* bq  = (const float*)d_in[3];
  const float* wk  = (const float*)d_in[4];
  const float* bk  = (const float*)d_in[5];
  const float* wv  = (const float*)d_in[6];
  const float* bv  = (const float*)d_in[7];
  const float* wfc = (const float*)d_in[8];
  const float* bfc = (const float*)d_in[9];
  const float* wpj = (const float*)d_in[10];
  const float* bpj = (const float*)d_in[11];
  const float* lng = (const float*)d_in[12];
  const float* lnb = (const float*)d_in[13];

  const size_t SZ_TOK = (size_t)4096 * 2048;  // 8.39M elems
  unsigned short* ws0 = (unsigned short*)d_ws;
  unsigned short* xqb = ws0;                       // packed query (later: O)
  unsigned short* xb  = xqb + SZ_TOK;              // packed x     (later: m)
  unsigned short* wp  = xb + SZ_TOK;               // packed weight slot (16.8M elems)
  unsigned short* Qb  = wp + (size_t)8192 * 2048;
  unsigned short* Kb  = Qb + SZ_TOK;
  unsigned short* Vb  = Kb + SZ_TOK;
  unsigned short* hb  = Vb + SZ_TOK;               // fc out, 4096x8192
  unsigned short* Ob  = xqb;                       // alias after Q GEMM
  float*          xr2 = (float*)Qb;                // alias after attention (spans Q+K)
  unsigned short* x2b = Vb;                        // alias after attention
  unsigned short* mb  = xb;                        // alias after V GEMM

  const int n8 = (int)(SZ_TOK / 8);
  k_pack<<<n8 / 256, 256, 0, stream>>>(qy, xqb, n8);
  k_pack<<<n8 / 256, 256, 0, stream>>>(x, xb, n8);

  dim3 gQ(16, 32);  // N=2048, M=4096
  k_pack_w<<<1024, 256, 0, stream>>>(wq, wp, 1024, 1024);
  k_gemm<<<gQ, 256, 0, stream>>>(xqb, wp, bq, Qb, 4096, 2048, 2048);
  k_pack_w<<<1024, 256, 0, stream>>>(wk, wp, 1024, 1024);
  k_gemm<<<gQ, 256, 0, stream>>>(xb, wp, bk, Kb, 4096, 2048, 2048);
  k_pack_w<<<1024, 256, 0, stream>>>(wv, wp, 1024, 1024);
  k_gemm<<<gQ, 256, 0, stream>>>(xb, wp, bv, Vb, 4096, 2048, 2048);

  k_attn<<<1024, 256, 0, stream>>>(Qb, Kb, Vb, Ob);
  k_ln_attn<<<4096, 256, 0, stream>>>(Ob, qy, x, lng, lnb, xr2, x2b);

  k_pack_w<<<4096, 256, 0, stream>>>(wfc, wp, 4096, 1024);
  dim3 gF(64, 32);  // N=8192, M=4096
  k_gemm<<<gF, 256, 0, stream>>>(x2b, wp, bfc, hb, 4096, 8192, 2048);
  k_act<<<16384, 256, 0, stream>>>((unsigned int*)hb);

  k_pack_w<<<4096, 256, 0, stream>>>(wpj, wp, 1024, 4096);
  dim3 gP(16, 32);  // N=2048, M=4096, K=8192
  k_gemm<<<gP, 256, 0, stream>>>(hb, wp, bpj, mb, 4096, 2048, 8192);

  k_ln_final<<<4096, 256, 0, stream>>>(mb, xr2, lng, lnb, (float*)d_out);
}

// Round 3
// 682.903 us; speedup vs baseline: 1.2161x; 1.1798x over previous
//
#include <hip/hip_runtime.h>

typedef __attribute__((ext_vector_type(8))) short bhalf8;
typedef __attribute__((ext_vector_type(4))) float floatx4;
typedef __attribute__((ext_vector_type(2))) float floatx2;
typedef __attribute__((ext_vector_type(4))) unsigned int uintx4;

#define MFMA16(a, b, c) __builtin_amdgcn_mfma_f32_16x16x32_bf16((a), (b), (c), 0, 0, 0)

__device__ __forceinline__ unsigned short f2bf(float f) {
  unsigned u = __builtin_bit_cast(unsigned, f);
  u += 0x7fffu + ((u >> 16) & 1u);
  return (unsigned short)(u >> 16);
}
__device__ __forceinline__ float bf2f(unsigned short h) {
  unsigned u = ((unsigned)h) << 16;
  return __builtin_bit_cast(float, u);
}

__device__ __forceinline__ void gload_lds16(const unsigned short* g, unsigned short* l) {
  __builtin_amdgcn_global_load_lds((__attribute__((address_space(1))) void*)(g),
                                   (__attribute__((address_space(3))) void*)(l), 16, 0, 0);
}

// ---------------- pack f32 -> bf16 (elementwise, 8/thread) ----------------
__global__ __launch_bounds__(256) void k_pack(const float* __restrict__ in,
                                              unsigned short* __restrict__ out, int n8) {
  int idx = blockIdx.x * blockDim.x + threadIdx.x;
  if (idx >= n8) return;
  const float* p = in + (size_t)idx * 8;
  floatx4 a = *(const floatx4*)p;
  floatx4 b = *(const floatx4*)(p + 4);
  bhalf8 r;
  r[0] = (short)f2bf(a[0]); r[1] = (short)f2bf(a[1]);
  r[2] = (short)f2bf(a[2]); r[3] = (short)f2bf(a[3]);
  r[4] = (short)f2bf(b[0]); r[5] = (short)f2bf(b[1]);
  r[6] = (short)f2bf(b[2]); r[7] = (short)f2bf(b[3]);
  *(bhalf8*)(out + (size_t)idx * 8) = r;
}

// ---------------- pack complex weight [O][I][2] f32 -> W' [2O][2I] bf16 ----
__global__ __launch_bounds__(256) void k_pack_w(const float* __restrict__ w,
                                                unsigned short* __restrict__ wp,
                                                int O, int I) {
  int idx = blockIdx.x * blockDim.x + threadIdx.x;
  int nI4 = I >> 2;
  if (idx >= O * nI4) return;
  int o = idx / nI4;
  int i4 = (idx - o * nI4) * 4;
  const float* src = w + ((size_t)o * I + i4) * 2;
  floatx4 a = *(const floatx4*)src;
  floatx4 b = *(const floatx4*)(src + 4);
  bhalf8 r0, r1;
  r0[0] = (short)f2bf(a[0]); r0[1] = (short)f2bf(-a[1]);
  r0[2] = (short)f2bf(a[2]); r0[3] = (short)f2bf(-a[3]);
  r0[4] = (short)f2bf(b[0]); r0[5] = (short)f2bf(-b[1]);
  r0[6] = (short)f2bf(b[2]); r0[7] = (short)f2bf(-b[3]);
  r1[0] = (short)f2bf(a[1]); r1[1] = (short)f2bf(a[0]);
  r1[2] = (short)f2bf(a[3]); r1[3] = (short)f2bf(a[2]);
  r1[4] = (short)f2bf(b[1]); r1[5] = (short)f2bf(b[0]);
  r1[6] = (short)f2bf(b[3]); r1[7] = (short)f2bf(b[2]);
  size_t I2 = (size_t)I * 2;
  *(bhalf8*)(wp + (size_t)(2 * o) * I2 + 2 * i4) = r0;
  *(bhalf8*)(wp + (size_t)(2 * o + 1) * I2 + 2 * i4) = r1;
}

// ---------------- GEMM 256x128 tile, BK=64, 8 waves, 3-buf pipelined -------
// C[M][N] = A[M][K_full] @ B[N][K_full]^T (+bias). 2 phases/K-tile:
//   {ds_read subtile | stage tile t+2 | barrier | 16 MFMA | barrier}
// boundary s_waitcnt vmcnt(6) BEFORE closing barrier (t+2's 6 loads in flight).
// T2 swizzle: slot' = slot ^ (row&7), pre-swizzled global src + swizzled read.
#define ASTRIDE 16384  // shorts: 256 rows x 64
#define BSTRIDE 8192   // shorts: 128 rows x 64
#define BUFSZ 24576
__global__ __launch_bounds__(512, 2) void k_gemm256(
    const unsigned short* __restrict__ A, int lda,
    const unsigned short* __restrict__ B, int ldb,
    const float* __restrict__ bias0, const float* __restrict__ bias1,
    unsigned short* __restrict__ C, int N, int K, int addBias, long long zStrideC) {
  __shared__ unsigned short lds[3 * BUFSZ];
  const int t = threadIdx.x, lane = t & 63, wid = t >> 6;
  const int wr = wid >> 2, wc = wid & 3;
  const int l15 = lane & 15, l4 = lane >> 4, sx = l15 & 7;
  const int bn = blockIdx.x, bm = blockIdx.y, z = blockIdx.z;

  const unsigned short* Ab = A + (size_t)z * K;
  const unsigned short* Bb = B + (size_t)z * K;
  unsigned short* Cb = C + (size_t)z * zStrideC;

  // staging source: lane covers row wid*8+(lane>>3) of each 64-row part,
  // 16B at swizzled col-slot u = (lane&7)^(lane>>3)  (involution of T2 swz)
  const int srow = wid * 8 + (lane >> 3);
  const int ssw = ((lane & 7) ^ (lane >> 3)) * 8;
  const unsigned short* gA = Ab + (size_t)(bm * 256 + srow) * lda + ssw;
  const unsigned short* gB = Bb + (size_t)(bn * 128 + srow) * ldb + ssw;

  const int NT = K >> 6;

  floatx4 acc[8][2];
#pragma unroll
  for (int m = 0; m < 8; ++m)
#pragma unroll
    for (int n = 0; n < 2; ++n) acc[m][n] = (floatx4)0.f;

  // prologue: stage K-tiles 0 and 1 (6 loads each per wave)
#pragma unroll
  for (int tt = 0; tt < 2; ++tt) {
    unsigned short* dst = &lds[tt * BUFSZ];
#pragma unroll
    for (int q = 0; q < 4; ++q)
      gload_lds16(gA + (size_t)q * 64 * lda + tt * 64, dst + q * 4096 + wid * 512);
#pragma unroll
    for (int q = 0; q < 2; ++q)
      gload_lds16(gB + (size_t)q * 64 * ldb + tt * 64, dst + ASTRIDE + q * 4096 + wid * 512);
  }
  asm volatile("s_waitcnt vmcnt(6)" ::: "memory");  // tile 0 landed, tile 1 in flight
  __builtin_amdgcn_s_barrier();

  for (int tk = 0; tk < NT; ++tk) {
    const int cur = tk % 3;
    const int nxt = (tk + 2) % 3;  // == (tk-1)%3: its readers finished last tile
    const bool doStage = (tk + 2 < NT);
    const unsigned short* lA = &lds[cur * BUFSZ];
    const unsigned short* lB = &lds[cur * BUFSZ + ASTRIDE];
    unsigned short* sD = &lds[nxt * BUFSZ];
    const size_t ko = (size_t)(tk + 2) * 64;

    bhalf8 af[4][2], bfv[2][2];
    // ---- phase 0: acc rows m=0..3 (reads all B frags too) ----
#pragma unroll
    for (int n = 0; n < 2; ++n) {
      int rb = wc * 32 + n * 16 + l15;
#pragma unroll
      for (int kk = 0; kk < 2; ++kk)
        bfv[n][kk] = *(const bhalf8*)&lB[rb * 64 + (((kk << 2) + l4) ^ sx) * 8];
    }
#pragma unroll
    for (int m = 0; m < 4; ++m) {
      int r = wr * 128 + m * 16 + l15;
#pragma unroll
      for (int kk = 0; kk < 2; ++kk)
        af[m][kk] = *(const bhalf8*)&lA[r * 64 + (((kk << 2) + l4) ^ sx) * 8];
    }
    if (doStage) {
      gload_lds16(gA + ko, sD + wid * 512);
      gload_lds16(gA + (size_t)64 * lda + ko, sD + 4096 + wid * 512);
      gload_lds16(gB + ko, sD + ASTRIDE + wid * 512);
    }
    asm volatile("" ::: "memory");
    __builtin_amdgcn_s_barrier();
    __builtin_amdgcn_s_setprio(1);
#pragma unroll
    for (int m = 0; m < 4; ++m)
#pragma unroll
      for (int n = 0; n < 2; ++n)
#pragma unroll
        for (int kk = 0; kk < 2; ++kk)
          acc[m][n] = MFMA16(af[m][kk], bfv[n][kk], acc[m][n]);
    __builtin_amdgcn_s_setprio(0);
    asm volatile("" ::: "memory");
    __builtin_amdgcn_s_barrier();

    // ---- phase 1: acc rows m=4..7 ----
#pragma unroll
    for (int m = 0; m < 4; ++m) {
      int r = wr * 128 + 64 + m * 16 + l15;
#pragma unroll
      for (int kk = 0; kk < 2; ++kk)
        af[m][kk] = *(const bhalf8*)&lA[r * 64 + (((kk << 2) + l4) ^ sx) * 8];
    }
    if (doStage) {
      gload_lds16(gA + (size_t)128 * lda + ko, sD + 8192 + wid * 512);
      gload_lds16(gA + (size_t)192 * lda + ko, sD + 12288 + wid * 512);
      gload_lds16(gB + (size_t)64 * ldb + ko, sD + ASTRIDE + 4096 + wid * 512);
    }
    asm volatile("" ::: "memory");
    __builtin_amdgcn_s_barrier();
    __builtin_amdgcn_s_setprio(1);
#pragma unroll
    for (int m = 0; m < 4; ++m)
#pragma unroll
      for (int n = 0; n < 2; ++n)
#pragma unroll
        for (int kk = 0; kk < 2; ++kk)
          acc[4 + m][n] = MFMA16(af[m][kk], bfv[n][kk], acc[4 + m][n]);
    __builtin_amdgcn_s_setprio(0);
    // K-tile boundary: drain tile t+1's loads (oldest 6), keep t+2's 6 in
    // flight; the barrier then publishes all waves' drained stages.
    if (tk + 2 < NT) {
      asm volatile("s_waitcnt vmcnt(6)" ::: "memory");
    } else if (tk + 1 < NT) {
      asm volatile("s_waitcnt vmcnt(0)" ::: "memory");
    }
    __builtin_amdgcn_s_barrier();
  }

  const int r0 = bm * 256 + wr * 128 + l4 * 4;
  const int c0 = bn * 128 + wc * 32 + l15;
#pragma unroll
  for (int m = 0; m < 8; ++m)
#pragma unroll
    for (int n = 0; n < 2; ++n) {
      int col = c0 + n * 16;
      float bv = 0.f;
      if (addBias) bv = (col < 2048) ? bias0[col] : bias1[col - 2048];
#pragma unroll
      for (int rr = 0; rr < 4; ++rr)
        Cb[(size_t)(r0 + m * 16 + rr) * N + col] = f2bf(acc[m][n][rr] + bv);
    }
}

// ---------------- complex flash attention -----------------------------------
// K,V fused buffer: kv[tok][0..2047]=K feats, kv[tok][2048..4095]=V feats.
__global__ __launch_bounds__(256) void k_attn(const unsigned short* __restrict__ Q,
                                              const unsigned short* __restrict__ kv,
                                              unsigned short* __restrict__ O) {
  __shared__ unsigned short Ks[32][136];
  __shared__ unsigned short Vt[128][40];
  __shared__ unsigned short Ps[4][2][16][40];

  const int t = threadIdx.x, lane = t & 63, wave = t >> 6;
  const int l15 = lane & 15, l4 = lane >> 4;
  const int bid = blockIdx.x;
  const int qt = bid & 7, h = (bid >> 3) & 15, b = bid >> 7;
  const int colbase = h * 128;
  const int qrow0 = b * 512 + qt * 64 + wave * 16;

  bhalf8 qf[4];
  {
    const unsigned short* qp = Q + (size_t)(qrow0 + l15) * 2048 + colbase + l4 * 8;
#pragma unroll
    for (int ks = 0; ks < 4; ks++) qf[ks] = *(const bhalf8*)(qp + ks * 32);
  }

  float m_s[2][4], l_s[2][4];
#pragma unroll
  for (int c = 0; c < 2; c++)
#pragma unroll
    for (int r = 0; r < 4; r++) { m_s[c][r] = -1e30f; l_s[c][r] = 0.f; }
  floatx4 oacc[2][8];
#pragma unroll
  for (int c = 0; c < 2; c++)
#pragma unroll
    for (int n = 0; n < 8; n++) oacc[c][n] = (floatx4)0.f;

  for (int kb = 0; kb < 16; kb++) {
    __syncthreads();
#pragma unroll
    for (int s = 0; s < 2; s++) {
      int c = t + s * 256;
      int kr = c >> 4, jc = (c & 15) * 8;
      *(bhalf8*)&Ks[kr][jc] =
          *(const bhalf8*)(kv + (size_t)(b * 512 + kb * 32 + kr) * 4096 + colbase + jc);
    }
#pragma unroll
    for (int s = 0; s < 2; s++) {
      int c = t + s * 256;
      int kr = c & 31, j0 = (c >> 5) * 8;
      bhalf8 vv =
          *(const bhalf8*)(kv + (size_t)(b * 512 + kb * 32 + kr) * 4096 + 2048 + colbase + j0);
#pragma unroll
      for (int i2 = 0; i2 < 8; i2++) Vt[j0 + i2][kr] = (unsigned short)vv[i2];
    }
    __syncthreads();

    floatx4 sacc[2][2];
#pragma unroll
    for (int c = 0; c < 2; c++) { sacc[c][0] = (floatx4)0.f; sacc[c][1] = (floatx4)0.f; }
#pragma unroll
    for (int ks = 0; ks < 4; ks++) {
#pragma unroll
      for (int n = 0; n < 2; n++) {
        bhalf8 kf = *(const bhalf8*)&Ks[n * 16 + l15][ks * 32 + l4 * 8];
        uintx4 ku = __builtin_bit_cast(uintx4, kf);
        uintx4 kneg = ku ^ 0x80000000u;
        uintx4 kswp = (ku >> 16) | (ku << 16);
        sacc[0][n] = MFMA16(qf[ks], __builtin_bit_cast(bhalf8, kneg), sacc[0][n]);
        sacc[1][n] = MFMA16(qf[ks], __builtin_bit_cast(bhalf8, kswp), sacc[1][n]);
      }
    }

    const float scale = 0.125f;
#pragma unroll
    for (int comp = 0; comp < 2; comp++) {
#pragma unroll
      for (int r = 0; r < 4; r++) {
        float v0 = sacc[comp][0][r] * scale;
        float v1 = sacc[comp][1][r] * scale;
        float vmax = fmaxf(v0, v1);
#pragma unroll
        for (int off = 1; off < 16; off <<= 1) vmax = fmaxf(vmax, __shfl_xor(vmax, off, 64));
        float mnew = fmaxf(m_s[comp][r], vmax);
        float cr = __expf(m_s[comp][r] - mnew);
        float p0 = __expf(v0 - mnew), p1 = __expf(v1 - mnew);
        float ps = p0 + p1;
#pragma unroll
        for (int off = 1; off < 16; off <<= 1) ps += __shfl_xor(ps, off, 64);
        l_s[comp][r] = l_s[comp][r] * cr + ps;
        m_s[comp][r] = mnew;
#pragma unroll
        for (int nn = 0; nn < 8; nn++) oacc[comp][nn][r] *= cr;
        int qr = l4 * 4 + r;
        Ps[wave][comp][qr][l15] = f2bf(p0);
        Ps[wave][comp][qr][16 + l15] = f2bf(p1);
      }
    }
    __syncthreads();

    bhalf8 par = *(const bhalf8*)&Ps[wave][0][l15][l4 * 8];
    bhalf8 pai = *(const bhalf8*)&Ps[wave][1][l15][l4 * 8];
#pragma unroll
    for (int nn = 0; nn < 8; nn++) {
      bhalf8 vf = *(const bhalf8*)&Vt[nn * 16 + l15][l4 * 8];
      uintx4 vu = __builtin_bit_cast(uintx4, vf);
      uintx4 vp;
#pragma unroll
      for (int i2 = 0; i2 < 4; i2++) vp[i2] = (unsigned)__shfl_xor((int)vu[i2], 1, 64);
      if (!(lane & 1)) vp ^= 0x80008000u;
      oacc[0][nn] = MFMA16(par, vf, oacc[0][nn]);
      oacc[1][nn] = MFMA16(pai, __builtin_bit_cast(bhalf8, vp), oacc[1][nn]);
    }
  }

#pragma unroll
  for (int nn = 0; nn < 8; nn++) {
#pragma unroll
    for (int r = 0; r < 4; r++) {
      float o = oacc[0][nn][r] / l_s[0][r] + oacc[1][nn][r] / l_s[1][r];
      int row = qrow0 + l4 * 4 + r;
      int col = colbase + nn * 16 + l15;
      O[(size_t)row * 2048 + col] = f2bf(o);
    }
  }
}

// ---------------- block reduction of 4 values across 256 threads ------------
__device__ __forceinline__ void block_reduce_4(float* v, float* sbuf, int t) {
  int lane = t & 63, wave = t >> 6;
#pragma unroll
  for (int i = 0; i < 4; i++) {
    float x = v[i];
#pragma unroll
    for (int off = 32; off > 0; off >>= 1) x += __shfl_xor(x, off, 64);
    if (lane == 0) sbuf[wave * 4 + i] = x;
  }
  __syncthreads();
#pragma unroll
  for (int i = 0; i < 4; i++) v[i] = sbuf[i] + sbuf[4 + i] + sbuf[8 + i] + sbuf[12 + i];
  __syncthreads();
}

// ---------------- post-attention: (O+q) -> LN0 -> (+x) -> LN1 ---------------
__global__ __launch_bounds__(256) void k_ln_attn(const unsigned short* __restrict__ O,
                                                 const float* __restrict__ qin,
                                                 const float* __restrict__ xin,
                                                 const float* __restrict__ g,
                                                 const float* __restrict__ bb,
                                                 float* __restrict__ xr2,
                                                 unsigned short* __restrict__ xr2b) {
  __shared__ float sbuf[16];
  const int row = blockIdx.x, t = threadIdx.x;
  const size_t base = (size_t)row * 2048;
  float tr[4], ti[4], acc[4] = {0.f, 0.f, 0.f, 0.f};
#pragma unroll
  for (int k = 0; k < 4; k++) {
    int d = k * 256 + t;
    unsigned op = *(const unsigned*)(O + base + 2 * d);
    floatx2 qp = *(const floatx2*)(qin + base + 2 * d);
    float a = bf2f((unsigned short)(op & 0xffffu)) + qp[0];
    float c = bf2f((unsigned short)(op >> 16)) + qp[1];
    tr[k] = a; ti[k] = c;
    acc[0] += a; acc[1] += a * a; acc[2] += c; acc[3] += c * c;
  }
  block_reduce_4(acc, sbuf, t);
  float mr = acc[0] * (1.f / 1024.f), vr = acc[1] * (1.f / 1024.f) - mr * mr;
  float mi = acc[2] * (1.f / 1024.f), vi = acc[3] * (1.f / 1024.f) - mi * mi;
  float ir = rsqrtf(vr + 1e-5f), ii = rsqrtf(vi + 1e-5f);
  float ur[4], ui[4], a2[4] = {0.f, 0.f, 0.f, 0.f};
#pragma unroll
  for (int k = 0; k < 4; k++) {
    int d = k * 256 + t;
    float u_r = (tr[k] - mr) * ir * g[d] + bb[d];
    float u_i = (ti[k] - mi) * ii * g[1024 + d] + bb[1024 + d];
    floatx2 xp = *(const floatx2*)(xin + base + 2 * d);
    float v_r = xp[0] + u_r, v_i = xp[1] + u_i;
    ur[k] = v_r; ui[k] = v_i;
    a2[0] += v_r; a2[1] += v_r * v_r; a2[2] += v_i; a2[3] += v_i * v_i;
  }
  block_reduce_4(a2, sbuf, t);
  float mr2 = a2[0] * (1.f / 1024.f), vr2 = a2[1] * (1.f / 1024.f) - mr2 * mr2;
  float mi2 = a2[2] * (1.f / 1024.f), vi2 = a2[3] * (1.f / 1024.f) - mi2 * mi2;
  float ir2 = rsqrtf(vr2 + 1e-5f), ii2 = rsqrtf(vi2 + 1e-5f);
#pragma unroll
  for (int k = 0; k < 4; k++) {
    int d = k * 256 + t;
    float w_r = (ur[k] - mr2) * ir2 * g[2048 + d] + bb[2048 + d];
    float w_i = (ui[k] - mi2) * ii2 * g[3072 + d] + bb[3072 + d];
    floatx2 o; o[0] = w_r; o[1] = w_i;
    *(floatx2*)(xr2 + base + 2 * d) = o;
    unsigned pk = ((unsigned)f2bf(w_i) << 16) | (unsigned)f2bf(w_r);
    *(unsigned*)(xr2b + base + 2 * d) = pk;
  }
}

// ---------------- modReLU-style activation, in place on bf16 pairs ----------
__global__ __launch_bounds__(256) void k_act(unsigned int* __restrict__ h) {
  size_t idx = (size_t)blockIdx.x * blockDim.x + threadIdx.x;
  uintx4 v = *(uintx4*)(h + idx * 4);
#pragma unroll
  for (int i = 0; i < 4; i++) {
    float hr = bf2f((unsigned short)(v[i] & 0xffffu));
    float hi = bf2f((unsigned short)(v[i] >> 16));
    float mag = sqrtf(hr * hr + hi * hi);
    float nr = 0.5f * (hr + mag), ni = 0.5f * hi;
    v[i] = ((unsigned)f2bf(ni) << 16) | (unsigned)f2bf(nr);
  }
  *(uintx4*)(h + idx * 4) = v;
}

// ---------------- final: (xr2 + p0 + p1 + bias) -> LN2 -> out ---------------
__global__ __launch_bounds__(256) void k_ln_final(const unsigned short* __restrict__ P0,
                                                  const unsigned short* __restrict__ P1,
                                                  const float* __restrict__ xr2,
                                                  const float* __restrict__ pbias,
                                                  const float* __restrict__ g,
                                                  const float* __restrict__ bb,
                                                  float* __restrict__ out) {
  __shared__ float sbuf[16];
  const int row = blockIdx.x, t = threadIdx.x;
  const size_t base = (size_t)row * 2048;
  float tr[4], ti[4], acc[4] = {0.f, 0.f, 0.f, 0.f};
#pragma unroll
  for (int k = 0; k < 4; k++) {
    int d = k * 256 + t;
    unsigned m0 = *(const unsigned*)(P0 + base + 2 * d);
    unsigned m1 = *(const unsigned*)(P1 + base + 2 * d);
    floatx2 xp = *(const floatx2*)(xr2 + base + 2 * d);
    floatx2 bp = *(const floatx2*)(pbias + 2 * d);
    float a = xp[0] + bp[0] + bf2f((unsigned short)(m0 & 0xffffu)) +
              bf2f((unsigned short)(m1 & 0xffffu));
    float c = xp[1] + bp[1] + bf2f((unsigned short)(m0 >> 16)) +
              bf2f((unsigned short)(m1 >> 16));
    tr[k] = a; ti[k] = c;
    acc[0] += a; acc[1] += a * a; acc[2] += c; acc[3] += c * c;
  }
  block_reduce_4(acc, sbuf, t);
  float mr = acc[0] * (1.f / 1024.f), vr = acc[1] * (1.f / 1024.f) - mr * mr;
  float mi = acc[2] * (1.f / 1024.f), vi = acc[3] * (1.f / 1024.f) - mi * mi;
  float ir = rsqrtf(vr + 1e-5f), ii = rsqrtf(vi + 1e-5f);
#pragma unroll
  for (int k = 0; k < 4; k++) {
    int d = k * 256 + t;
    float w_r = (tr[k] - mr) * ir * g[4096 + d] + bb[4096 + d];
    float w_i = (ti[k] - mi) * ii * g[5120 + d] + bb[5120 + d];
    floatx2 o; o[0] = w_r; o[1] = w_i;
    *(floatx2*)(out + base + 2 * d) = o;
  }
}

extern "C" void kernel_launch(void* const* d_in, const int* in_sizes, int n_in,
                              void* d_out, int out_size, void* d_ws, size_t ws_size,
                              hipStream_t stream) {
  const float* x   = (const float*)d_in[0];
  const float* qy  = (const float*)d_in[1];
  const float* wq  = (const float*)d_in[2];
  const float* bq  = (const float*)d_in[3];
  const float* wk  = (const float*)d_in[4];
  const float* bk  = (const float*)d_in[5];
  const float* wv  = (const float*)d_in[6];
  const float* bv  = (const float*)d_in[7];
  const float* wfc = (const float*)d_in[8];
  const float* bfc = (const float*)d_in[9];
  const float* wpj = (const float*)d_in[10];
  const float* bpj = (const float*)d_in[11];
  const float* lng = (const float*)d_in[12];
  const float* lnb = (const float*)d_in[13];

  const size_t SZ_TOK = (size_t)4096 * 2048;
  unsigned short* ws0 = (unsigned short*)d_ws;
  unsigned short* xqb = ws0;                    // packed query; later O; later proj p0
  unsigned short* xb  = xqb + SZ_TOK;           // packed x; later proj p1
  unsigned short* wp  = xb + SZ_TOK;            // packed weight slot (2*SZ_TOK shorts)
  unsigned short* Qb  = wp + 2 * SZ_TOK;        // Q out; later xr2 (spans KVb half)
  unsigned short* KVb = Qb + SZ_TOK;            // fused K|V out (2*SZ_TOK shorts)
  unsigned short* hb  = Qb + 3 * SZ_TOK;        // fc out (4*SZ_TOK shorts)
  unsigned short* Ob  = xqb;
  float*          xr2 = (float*)Qb;
  unsigned short* x2b = Qb + 2 * SZ_TOK;

  const int n8 = (int)(SZ_TOK / 8);
  k_pack<<<n8 / 256, 256, 0, stream>>>(qy, xqb, n8);
  k_pack<<<n8 / 256, 256, 0, stream>>>(x, xb, n8);

  // Q = query @ Wq'^T + bq     (M=4096,N=2048,K=2048) -> 256 blocks
  k_pack_w<<<1024, 256, 0, stream>>>(wq, wp, 1024, 1024);
  k_gemm256<<<dim3(16, 16, 1), 512, 0, stream>>>(xqb, 2048, wp, 2048, bq, bq, Qb,
                                                 2048, 2048, 1, 0);
  // KV fused: B = [Wk'; Wv']   (N=4096) -> 512 blocks
  k_pack_w<<<1024, 256, 0, stream>>>(wk, wp, 1024, 1024);
  k_pack_w<<<1024, 256, 0, stream>>>(wv, wp + (size_t)2048 * 2048, 1024, 1024);
  k_gemm256<<<dim3(32, 16, 1), 512, 0, stream>>>(xb, 2048, wp, 2048, bk, bv, KVb,
                                                 4096, 2048, 1, 0);

  k_attn<<<1024, 256, 0, stream>>>(Qb, KVb, Ob);
  k_ln_attn<<<4096, 256, 0, stream>>>(Ob, qy, x, lng, lnb, xr2, x2b);

  // fc: (M=4096,N=8192,K=2048) -> 1024 blocks
  k_pack_w<<<4096, 256, 0, stream>>>(wfc, wp, 4096, 1024);
  k_gemm256<<<dim3(64, 16, 1), 512, 0, stream>>>(x2b, 2048, wp, 2048, bfc, bfc + 2048,
                                                 hb, 8192, 2048, 1, 0);
  k_act<<<16384, 256, 0, stream>>>((unsigned int*)hb);

  // proj split-K=2: z in {0,1}, K=4096 each, bf16 partials into xqb/xb
  k_pack_w<<<4096, 256, 0, stream>>>(wpj, wp, 1024, 4096);
  k_gemm256<<<dim3(16, 16, 2), 512, 0, stream>>>(hb, 8192, wp, 8192, bpj, bpj, xqb,
                                                 2048, 4096, 0, (long long)SZ_TOK);

  k_ln_final<<<4096, 256, 0, stream>>>(xqb, xb, xr2, bpj, lng, lnb, (float*)d_out);
}